// Round 2
// baseline (1719.397 us; speedup 1.0000x reference)
//
#include <hip/hip_runtime.h>
#include <hip/hip_bf16.h>
#include <stdint.h>

// GraphSAGE layer, N=16384, F_IN=F_OUT=256.
// out = (adj@ (x@W1))/deg + x@W2 + bias
//   K0: WT[n][k] (bf16)  = transpose of [W1|W2]
//   K1: yT[n][m] (bf16)  = (x@W1)^T ;  z[m][n] (f32) = x@W2 + bias
//   K2: out[m][n] = (adj @ y)[m][n]/deg[m] + z[m][n]   (adj read once, deg fused)
// K2 v2: dbuf LDS + loads-after-barrier pipeline + conflict-free LDS
//        (A padded stride 40 halfwords; B XOR-swizzle absorbed in global addr,
//         staged via global_load_lds width=16)

typedef short bf16x8 __attribute__((ext_vector_type(8)));
typedef float f32x4  __attribute__((ext_vector_type(4)));

__device__ __forceinline__ uint32_t pack_bf16_rne(float lo, float hi) {
    uint32_t ul = __float_as_uint(lo);
    uint32_t uh = __float_as_uint(hi);
    ul = (ul + 0x7fffu + ((ul >> 16) & 1u)) >> 16;
    uh = (uh + 0x7fffu + ((uh >> 16) & 1u)) >> 16;
    return ul | (uh << 16);
}

__device__ __forceinline__ void gload_lds16(const void* g, void* l) {
    __builtin_amdgcn_global_load_lds(
        (__attribute__((address_space(1))) void*)g,
        (__attribute__((address_space(3))) void*)l, 16, 0, 0);
}

// ---------------- K0: transpose weight [512,256] f32 -> WT [512(n)][256(k)] bf16
__global__ __launch_bounds__(256) void k_transpose_w(const float* __restrict__ w,
                                                     uint16_t* __restrict__ wt) {
    int idx = blockIdx.x * 256 + threadIdx.x;   // 0..131071
    int n = idx >> 8;
    int k = idx & 255;
    int row = (n < 256) ? k : (256 + k);
    int col = (n < 256) ? n : (n - 256);
    uint32_t u = __float_as_uint(w[row * 256 + col]);
    u = (u + 0x7fffu + ((u >> 16) & 1u)) >> 16;
    wt[idx] = (uint16_t)u;
}

// ---------------- K1: small GEMM  [16384,256] @ [256,512] -> yT (cols 0..255) / z (cols 256..511)
__global__ __launch_bounds__(256) void k_small_gemm(const float* __restrict__ x,
                                                    const uint16_t* __restrict__ wt,
                                                    const float* __restrict__ bias,
                                                    uint16_t* __restrict__ yT,
                                                    float* __restrict__ z) {
    __shared__ uint16_t As[128 * 32];  // [m][k] bf16
    __shared__ uint16_t Bs[128 * 32];  // [n][k] bf16

    const int t  = threadIdx.x;
    const int ct = blockIdx.x;        // 0..3
    const int rt = blockIdx.y;        // 0..127
    const int m0 = rt * 128;
    const int n0 = ct * 128;

    const int lane = t & 63, w = t >> 6;
    const int wr = w >> 1, wc = w & 1;
    const int l15 = lane & 15, quad = lane >> 4;

    f32x4 acc[4][4] = {};

    float4 a_reg[4];
    uint4  b_reg[2];

#pragma unroll
    for (int i = 0; i < 4; ++i) {
        int f4 = t + 256 * i, row = f4 >> 3, c4 = f4 & 7;
        a_reg[i] = *(const float4*)(x + (m0 + row) * 256 + c4 * 4);
    }
#pragma unroll
    for (int i = 0; i < 2; ++i) {
        int u4 = t + 256 * i, n_l = u4 >> 2, part = u4 & 3;
        b_reg[i] = *(const uint4*)(wt + (n0 + n_l) * 256 + part * 8);
    }

    for (int kk = 0; kk < 8; ++kk) {
        __syncthreads();
#pragma unroll
        for (int i = 0; i < 4; ++i) {
            int f4 = t + 256 * i, row = f4 >> 3, c4 = f4 & 7;
            uint2 p;
            p.x = pack_bf16_rne(a_reg[i].x, a_reg[i].y);
            p.y = pack_bf16_rne(a_reg[i].z, a_reg[i].w);
            *(uint2*)(As + row * 32 + c4 * 4) = p;
        }
#pragma unroll
        for (int i = 0; i < 2; ++i) {
            int u4 = t + 256 * i, n_l = u4 >> 2, part = u4 & 3;
            *(uint4*)(Bs + n_l * 32 + part * 8) = b_reg[i];
        }
        if (kk < 7) {
            int k0 = (kk + 1) * 32;
#pragma unroll
            for (int i = 0; i < 4; ++i) {
                int f4 = t + 256 * i, row = f4 >> 3, c4 = f4 & 7;
                a_reg[i] = *(const float4*)(x + (m0 + row) * 256 + k0 + c4 * 4);
            }
#pragma unroll
            for (int i = 0; i < 2; ++i) {
                int u4 = t + 256 * i, n_l = u4 >> 2, part = u4 & 3;
                b_reg[i] = *(const uint4*)(wt + (n0 + n_l) * 256 + k0 + part * 8);
            }
        }
        __syncthreads();

        bf16x8 a_frag[4], b_frag[4];
#pragma unroll
        for (int fr = 0; fr < 4; ++fr)
            a_frag[fr] = *(const bf16x8*)(As + (wr * 64 + fr * 16 + l15) * 32 + quad * 8);
#pragma unroll
        for (int fc = 0; fc < 4; ++fc)
            b_frag[fc] = *(const bf16x8*)(Bs + (wc * 64 + fc * 16 + l15) * 32 + quad * 8);
#pragma unroll
        for (int fr = 0; fr < 4; ++fr)
#pragma unroll
            for (int fc = 0; fc < 4; ++fc)
                acc[fr][fc] = __builtin_amdgcn_mfma_f32_16x16x32_bf16(
                    a_frag[fr], b_frag[fc], acc[fr][fc], 0, 0, 0);
    }

    if (ct < 2) {
#pragma unroll
        for (int fr = 0; fr < 4; ++fr) {
            int m_base = m0 + wr * 64 + fr * 16 + quad * 4;
#pragma unroll
            for (int fc = 0; fc < 4; ++fc) {
                int n_g = n0 + wc * 64 + fc * 16 + l15;   // 0..255
                uint2 pp;
                pp.x = pack_bf16_rne(acc[fr][fc][0], acc[fr][fc][1]);
                pp.y = pack_bf16_rne(acc[fr][fc][2], acc[fr][fc][3]);
                *(uint2*)(yT + (size_t)n_g * 16384 + m_base) = pp;
            }
        }
    } else {
#pragma unroll
        for (int fr = 0; fr < 4; ++fr) {
            int m_base = m0 + wr * 64 + fr * 16 + quad * 4;
#pragma unroll
            for (int fc = 0; fc < 4; ++fc) {
                int n_g = (n0 - 256) + wc * 64 + fc * 16 + l15;  // 0..255
                float bv = bias[n_g];
#pragma unroll
                for (int r = 0; r < 4; ++r)
                    z[(size_t)(m_base + r) * 256 + n_g] = acc[fr][fc][r] + bv;
            }
        }
    }
}

// ---------------- K2 v2: out[16384,256] = (adj @ y)/deg + z
// 256 blocks x 512 threads (8 waves; wave = 32 rows x 64 cols), BK=32, 512 iters.
// Double-buffered LDS, loads issued right after the barrier, consumed just
// before the next one (vmcnt(0)-at-barrier drain is then hidden by MFMA phase).
#define A_STRIDE 40                 // 64 rows x 40 halfwords (pad 32->40, 80B = 16-aligned)
#define A_SZ (64 * A_STRIDE)        // 2560 halfwords
#define B_SZ (256 * 32)             // 8192 halfwords, unpadded + XOR swizzle
__global__ __launch_bounds__(512, 2) void k_big_gemm(const int* __restrict__ adj,
                                                     const uint16_t* __restrict__ yT,
                                                     const float* __restrict__ z,
                                                     float* __restrict__ out) {
    __shared__ uint16_t As_f[2 * A_SZ];   //  10 KB
    __shared__ uint16_t Bs_f[2 * B_SZ];   //  32 KB
    __shared__ int degs[64];

    const int t = threadIdx.x;
    const int m0 = blockIdx.x * 64;
    const int lane = t & 63, w = t >> 6;           // w 0..7
    const int wr = w >> 2, wc = w & 3;             // wave: 2 row frags, 4 col frags
    const int l15 = lane & 15, quad = lane >> 4;

    f32x4 acc[2][4] = {};

    // ---- A staging: 64 rows x 32 ints / iter = 512 int4, one per thread
    const int a_n = t >> 3, a_c4 = t & 7;          // row, 4-int chunk
    const int4* pa4 = (const int4*)(adj + (size_t)(m0 + a_n) * 16384) + a_c4;
    const int a_lds = a_n * A_STRIDE + a_c4 * 4;   // halfword offset (uint2 dest)

    // ---- B staging: 256 rows x 32 bf16 / iter = 1024 16B-slots; 2 global_load_lds/thread
    // slot s: n = s>>2, c' = s&3 (LDS chunk); global chunk c = c' ^ ((n>>1)&3)
    const uint16_t* pbg[2];
    int b_ldsbase[2];
#pragma unroll
    for (int i = 0; i < 2; ++i) {
        int base = (w * 2 + i) * 64;
        int s = base + lane;
        int bn = s >> 2;
        int bc = (s & 3) ^ ((bn >> 1) & 3);
        pbg[i] = yT + (size_t)bn * 16384 + bc * 8;
        b_ldsbase[i] = base * 8;                   // halfword offset, lane lands at +lane*8
    }

    // ---- prologue: fill buffer 0 (kk = 0)
#pragma unroll
    for (int i = 0; i < 2; ++i) {
        gload_lds16(pbg[i], &Bs_f[b_ldsbase[i]]);
        pbg[i] += 32;
    }
    int4 a = pa4[0]; pa4 += 8;
    int degp = a.x + a.y + a.z + a.w;
    {
        uint2 pv;
        pv.x = (uint32_t)(a.x | (a.y << 16)) * 0x3F80u;
        pv.y = (uint32_t)(a.z | (a.w << 16)) * 0x3F80u;
        *(uint2*)&As_f[a_lds] = pv;
    }
    __syncthreads();

    for (int kk = 0; kk < 512; ++kk) {
        const int p = kk & 1;
        int4 an;
        if (kk < 511) {
            // issue next-iteration loads immediately after the barrier;
            // they stay in flight through the fragread+MFMA phase below
            an = pa4[0]; pa4 += 8;
#pragma unroll
            for (int i = 0; i < 2; ++i) {
                gload_lds16(pbg[i], &Bs_f[(1 - p) * B_SZ + b_ldsbase[i]]);
                pbg[i] += 32;
            }
        }

        const uint16_t* Ar = As_f + p * A_SZ;
        const uint16_t* Br = Bs_f + p * B_SZ;
        bf16x8 af[2], bfr[4];
#pragma unroll
        for (int fr = 0; fr < 2; ++fr) {
            int row = wr * 32 + fr * 16 + l15;
            af[fr] = *(const bf16x8*)(Ar + row * A_STRIDE + quad * 8);
        }
#pragma unroll
        for (int fc = 0; fc < 4; ++fc) {
            int n = wc * 64 + fc * 16 + l15;
            int cs = quad ^ ((n >> 1) & 3);
            bfr[fc] = *(const bf16x8*)(Br + n * 32 + cs * 8);
        }
#pragma unroll
        for (int fr = 0; fr < 2; ++fr)
#pragma unroll
            for (int fc = 0; fc < 4; ++fc)
                acc[fr][fc] = __builtin_amdgcn_mfma_f32_16x16x32_bf16(
                    af[fr], bfr[fc], acc[fr][fc], 0, 0, 0);

        if (kk < 511) {
            degp += an.x + an.y + an.z + an.w;
            uint2 pv;
            pv.x = (uint32_t)(an.x | (an.y << 16)) * 0x3F80u;
            pv.y = (uint32_t)(an.z | (an.w << 16)) * 0x3F80u;
            *(uint2*)&As_f[(1 - p) * A_SZ + a_lds] = pv;
        }
        __syncthreads();
    }

    // deg: row a_n owned by 8 consecutive lanes (t&7)
    degp += __shfl_down(degp, 4);
    degp += __shfl_down(degp, 2);
    degp += __shfl_down(degp, 1);
    if ((t & 7) == 0) degs[a_n] = degp;
    __syncthreads();

    // epilogue: out = acc/deg + z
#pragma unroll
    for (int fr = 0; fr < 2; ++fr) {
#pragma unroll
        for (int r = 0; r < 4; ++r) {
            int m_l = wr * 32 + fr * 16 + quad * 4 + r;
            float inv = 1.0f / (float)degs[m_l];
            size_t mrow = (size_t)(m0 + m_l) * 256;
#pragma unroll
            for (int fc = 0; fc < 4; ++fc) {
                int n_g = wc * 64 + fc * 16 + l15;
                out[mrow + n_g] = acc[fr][fc][r] * inv + z[mrow + n_g];
            }
        }
    }
}

extern "C" void kernel_launch(void* const* d_in, const int* in_sizes, int n_in,
                              void* d_out, int out_size, void* d_ws, size_t ws_size,
                              hipStream_t stream) {
    const float* x      = (const float*)d_in[0];
    const int*   adj    = (const int*)d_in[1];
    const float* weight = (const float*)d_in[2];
    const float* bias   = (const float*)d_in[3];
    float* out = (float*)d_out;

    uint16_t* wt = (uint16_t*)d_ws;
    uint16_t* yT = (uint16_t*)((char*)d_ws + 262144);
    float*    z  = (float*)((char*)d_ws + 262144 + 8388608);

    k_transpose_w<<<512, 256, 0, stream>>>(weight, wt);
    k_small_gemm<<<dim3(4, 128), 256, 0, stream>>>(x, wt, bias, yT, z);
    k_big_gemm<<<256, 512, 0, stream>>>(adj, yT, z, out);
}

// Round 3
// 1524.722 us; speedup vs baseline: 1.1277x; 1.1277x over previous
//
#include <hip/hip_runtime.h>
#include <hip/hip_bf16.h>
#include <stdint.h>

// GraphSAGE layer, N=16384, F_IN=F_OUT=256.
// out = (adj@ (x@W1))/deg + x@W2 + bias
//   K0: WT[n][k] (bf16)  = transpose of [W1|W2]
//   K1: yT[n][m] (bf16)  = (x@W1)^T ;  z[m][n] (f32) = x@W2 + bias
//   K2 v3: SPLIT-K 2-way (512 blocks -> 2 blocks/CU so the vmcnt(0)-at-barrier
//          drain of one block overlaps the sibling block's compute).
//          partial[ky][m][n], degw[ky][m] to workspace.
//   K3: out = (p0+p1)/(d0+d1) + z

typedef short bf16x8 __attribute__((ext_vector_type(8)));
typedef float f32x4  __attribute__((ext_vector_type(4)));

__device__ __forceinline__ uint32_t pack_bf16_rne(float lo, float hi) {
    uint32_t ul = __float_as_uint(lo);
    uint32_t uh = __float_as_uint(hi);
    ul = (ul + 0x7fffu + ((ul >> 16) & 1u)) >> 16;
    uh = (uh + 0x7fffu + ((uh >> 16) & 1u)) >> 16;
    return ul | (uh << 16);
}

__device__ __forceinline__ void gload_lds16(const void* g, void* l) {
    __builtin_amdgcn_global_load_lds(
        (__attribute__((address_space(1))) void*)g,
        (__attribute__((address_space(3))) void*)l, 16, 0, 0);
}

// ---------------- K0: transpose weight [512,256] f32 -> WT [512(n)][256(k)] bf16
__global__ __launch_bounds__(256) void k_transpose_w(const float* __restrict__ w,
                                                     uint16_t* __restrict__ wt) {
    int idx = blockIdx.x * 256 + threadIdx.x;   // 0..131071
    int n = idx >> 8;
    int k = idx & 255;
    int row = (n < 256) ? k : (256 + k);
    int col = (n < 256) ? n : (n - 256);
    uint32_t u = __float_as_uint(w[row * 256 + col]);
    u = (u + 0x7fffu + ((u >> 16) & 1u)) >> 16;
    wt[idx] = (uint16_t)u;
}

// ---------------- K1: small GEMM  [16384,256] @ [256,512] -> yT (cols 0..255) / z (cols 256..511)
__global__ __launch_bounds__(256) void k_small_gemm(const float* __restrict__ x,
                                                    const uint16_t* __restrict__ wt,
                                                    const float* __restrict__ bias,
                                                    uint16_t* __restrict__ yT,
                                                    float* __restrict__ z) {
    __shared__ uint16_t As[128 * 32];  // [m][k] bf16
    __shared__ uint16_t Bs[128 * 32];  // [n][k] bf16

    const int t  = threadIdx.x;
    const int ct = blockIdx.x;        // 0..3
    const int rt = blockIdx.y;        // 0..127
    const int m0 = rt * 128;
    const int n0 = ct * 128;

    const int lane = t & 63, w = t >> 6;
    const int wr = w >> 1, wc = w & 1;
    const int l15 = lane & 15, quad = lane >> 4;

    f32x4 acc[4][4] = {};

    float4 a_reg[4];
    uint4  b_reg[2];

#pragma unroll
    for (int i = 0; i < 4; ++i) {
        int f4 = t + 256 * i, row = f4 >> 3, c4 = f4 & 7;
        a_reg[i] = *(const float4*)(x + (m0 + row) * 256 + c4 * 4);
    }
#pragma unroll
    for (int i = 0; i < 2; ++i) {
        int u4 = t + 256 * i, n_l = u4 >> 2, part = u4 & 3;
        b_reg[i] = *(const uint4*)(wt + (n0 + n_l) * 256 + part * 8);
    }

    for (int kk = 0; kk < 8; ++kk) {
        __syncthreads();
#pragma unroll
        for (int i = 0; i < 4; ++i) {
            int f4 = t + 256 * i, row = f4 >> 3, c4 = f4 & 7;
            uint2 p;
            p.x = pack_bf16_rne(a_reg[i].x, a_reg[i].y);
            p.y = pack_bf16_rne(a_reg[i].z, a_reg[i].w);
            *(uint2*)(As + row * 32 + c4 * 4) = p;
        }
#pragma unroll
        for (int i = 0; i < 2; ++i) {
            int u4 = t + 256 * i, n_l = u4 >> 2, part = u4 & 3;
            *(uint4*)(Bs + n_l * 32 + part * 8) = b_reg[i];
        }
        if (kk < 7) {
            int k0 = (kk + 1) * 32;
#pragma unroll
            for (int i = 0; i < 4; ++i) {
                int f4 = t + 256 * i, row = f4 >> 3, c4 = f4 & 7;
                a_reg[i] = *(const float4*)(x + (m0 + row) * 256 + k0 + c4 * 4);
            }
#pragma unroll
            for (int i = 0; i < 2; ++i) {
                int u4 = t + 256 * i, n_l = u4 >> 2, part = u4 & 3;
                b_reg[i] = *(const uint4*)(wt + (n0 + n_l) * 256 + k0 + part * 8);
            }
        }
        __syncthreads();

        bf16x8 a_frag[4], b_frag[4];
#pragma unroll
        for (int fr = 0; fr < 4; ++fr)
            a_frag[fr] = *(const bf16x8*)(As + (wr * 64 + fr * 16 + l15) * 32 + quad * 8);
#pragma unroll
        for (int fc = 0; fc < 4; ++fc)
            b_frag[fc] = *(const bf16x8*)(Bs + (wc * 64 + fc * 16 + l15) * 32 + quad * 8);
#pragma unroll
        for (int fr = 0; fr < 4; ++fr)
#pragma unroll
            for (int fc = 0; fc < 4; ++fc)
                acc[fr][fc] = __builtin_amdgcn_mfma_f32_16x16x32_bf16(
                    a_frag[fr], b_frag[fc], acc[fr][fc], 0, 0, 0);
    }

    if (ct < 2) {
#pragma unroll
        for (int fr = 0; fr < 4; ++fr) {
            int m_base = m0 + wr * 64 + fr * 16 + quad * 4;
#pragma unroll
            for (int fc = 0; fc < 4; ++fc) {
                int n_g = n0 + wc * 64 + fc * 16 + l15;   // 0..255
                uint2 pp;
                pp.x = pack_bf16_rne(acc[fr][fc][0], acc[fr][fc][1]);
                pp.y = pack_bf16_rne(acc[fr][fc][2], acc[fr][fc][3]);
                *(uint2*)(yT + (size_t)n_g * 16384 + m_base) = pp;
            }
        }
    } else {
#pragma unroll
        for (int fr = 0; fr < 4; ++fr) {
            int m_base = m0 + wr * 64 + fr * 16 + quad * 4;
#pragma unroll
            for (int fc = 0; fc < 4; ++fc) {
                int n_g = (n0 - 256) + wc * 64 + fc * 16 + l15;  // 0..255
                float bv = bias[n_g];
#pragma unroll
                for (int r = 0; r < 4; ++r)
                    z[(size_t)(m_base + r) * 256 + n_g] = acc[fr][fc][r] + bv;
            }
        }
    }
}

// ---------------- K2 v3: partial[ky] = adj[:, ky-half] @ y[ky-half, :]
// grid (256 row-tiles, 2 k-halves), 512 threads (8 waves; wave = 32x64), BK=32, 256 iters.
// 2 blocks/CU: sibling block computes through this block's vmcnt(0) barrier drain.
#define A_STRIDE 40                 // 64 rows x 40 halfwords (80B row = conflict-free)
#define A_SZ (64 * A_STRIDE)
#define B_SZ (256 * 32)             // XOR-swizzled, unpadded (global_load_lds dest)
#define KITER 256
__global__ __launch_bounds__(512, 4) void k_big_gemm(const int* __restrict__ adj,
                                                     const uint16_t* __restrict__ yT,
                                                     float* __restrict__ part,
                                                     int* __restrict__ degw) {
    __shared__ uint16_t As_f[2 * A_SZ];   //  10 KB
    __shared__ uint16_t Bs_f[2 * B_SZ];   //  32 KB

    const int t = threadIdx.x;
    const int m0 = blockIdx.x * 64;
    const int ky = blockIdx.y;                     // k-half
    const int kbase = ky * 8192;                   // element offset into k
    const int lane = t & 63, w = t >> 6;
    const int wr = w >> 2, wc = w & 3;             // wave: 2 row frags, 4 col frags
    const int l15 = lane & 15, quad = lane >> 4;

    f32x4 acc[2][4] = {};

    // A staging: 64 rows x 32 ints / iter = 512 int4, one per thread
    const int a_n = t >> 3, a_c4 = t & 7;
    const int4* pa4 = (const int4*)(adj + (size_t)(m0 + a_n) * 16384 + kbase) + a_c4;
    const int a_lds = a_n * A_STRIDE + a_c4 * 4;

    // B staging: 256 rows x 32 bf16 / iter = 1024 16B slots, 2 global_load_lds/thread
    const uint16_t* pbg[2];
    int b_ldsbase[2];
#pragma unroll
    for (int i = 0; i < 2; ++i) {
        int base = (w * 2 + i) * 64;
        int s = base + lane;
        int bn = s >> 2;
        int bc = (s & 3) ^ ((bn >> 1) & 3);        // XOR swizzle absorbed in global addr
        pbg[i] = yT + (size_t)bn * 16384 + kbase + bc * 8;
        b_ldsbase[i] = base * 8;
    }

    // prologue: fill buffer 0
#pragma unroll
    for (int i = 0; i < 2; ++i) {
        gload_lds16(pbg[i], &Bs_f[b_ldsbase[i]]);
        pbg[i] += 32;
    }
    int4 a = pa4[0]; pa4 += 8;
    int degp = a.x + a.y + a.z + a.w;
    {
        uint2 pv;
        pv.x = (uint32_t)(a.x | (a.y << 16)) * 0x3F80u;
        pv.y = (uint32_t)(a.z | (a.w << 16)) * 0x3F80u;
        *(uint2*)&As_f[a_lds] = pv;
    }
    __syncthreads();

    for (int kk = 0; kk < KITER; ++kk) {
        const int p = kk & 1;
        int4 an;
        if (kk < KITER - 1) {
            an = pa4[0]; pa4 += 8;
#pragma unroll
            for (int i = 0; i < 2; ++i) {
                gload_lds16(pbg[i], &Bs_f[(1 - p) * B_SZ + b_ldsbase[i]]);
                pbg[i] += 32;
            }
        }

        const uint16_t* Ar = As_f + p * A_SZ;
        const uint16_t* Br = Bs_f + p * B_SZ;
        bf16x8 af[2], bfr[4];
#pragma unroll
        for (int fr = 0; fr < 2; ++fr) {
            int row = wr * 32 + fr * 16 + l15;
            af[fr] = *(const bf16x8*)(Ar + row * A_STRIDE + quad * 8);
        }
#pragma unroll
        for (int fc = 0; fc < 4; ++fc) {
            int n = wc * 64 + fc * 16 + l15;
            int cs = quad ^ ((n >> 1) & 3);
            bfr[fc] = *(const bf16x8*)(Br + n * 32 + cs * 8);
        }
#pragma unroll
        for (int fr = 0; fr < 2; ++fr)
#pragma unroll
            for (int fc = 0; fc < 4; ++fc)
                acc[fr][fc] = __builtin_amdgcn_mfma_f32_16x16x32_bf16(
                    af[fr], bfr[fc], acc[fr][fc], 0, 0, 0);

        if (kk < KITER - 1) {
            degp += an.x + an.y + an.z + an.w;
            uint2 pv;
            pv.x = (uint32_t)(an.x | (an.y << 16)) * 0x3F80u;
            pv.y = (uint32_t)(an.z | (an.w << 16)) * 0x3F80u;
            *(uint2*)&As_f[(1 - p) * A_SZ + a_lds] = pv;
        }
        __syncthreads();
    }

    // partial deg: row a_n owned by 8 consecutive lanes
    degp += __shfl_down(degp, 4);
    degp += __shfl_down(degp, 2);
    degp += __shfl_down(degp, 1);
    if ((t & 7) == 0) degw[ky * 16384 + m0 + a_n] = degp;

    // partial C
    float* pc = part + (size_t)ky * 16384 * 256;
#pragma unroll
    for (int fr = 0; fr < 2; ++fr) {
#pragma unroll
        for (int r = 0; r < 4; ++r) {
            int m_l = wr * 32 + fr * 16 + quad * 4 + r;
            size_t mrow = (size_t)(m0 + m_l) * 256;
#pragma unroll
            for (int fc = 0; fc < 4; ++fc) {
                int n_g = wc * 64 + fc * 16 + l15;
                pc[mrow + n_g] = acc[fr][fc][r];
            }
        }
    }
}

// ---------------- K3: out = (p0+p1)/(d0+d1) + z
__global__ __launch_bounds__(256) void k_reduce(const float* __restrict__ part,
                                                const int* __restrict__ degw,
                                                const float* __restrict__ z,
                                                float* __restrict__ out) {
    int i4 = blockIdx.x * 256 + threadIdx.x;       // float4 index, 64 per row
    int m = i4 >> 6;
    float4 p0 = ((const float4*)part)[i4];
    float4 p1 = ((const float4*)part)[i4 + 16384 * 64];
    float4 zz = ((const float4*)z)[i4];
    float inv = 1.0f / (float)(degw[m] + degw[16384 + m]);
    float4 o;
    o.x = (p0.x + p1.x) * inv + zz.x;
    o.y = (p0.y + p1.y) * inv + zz.y;
    o.z = (p0.z + p1.z) * inv + zz.z;
    o.w = (p0.w + p1.w) * inv + zz.w;
    ((float4*)out)[i4] = o;
}

extern "C" void kernel_launch(void* const* d_in, const int* in_sizes, int n_in,
                              void* d_out, int out_size, void* d_ws, size_t ws_size,
                              hipStream_t stream) {
    const float* x      = (const float*)d_in[0];
    const int*   adj    = (const int*)d_in[1];
    const float* weight = (const float*)d_in[2];
    const float* bias   = (const float*)d_in[3];
    float* out = (float*)d_out;

    // ws: WT 256KB | yT 8MB | z 16MB | part 33.5MB | degw 128KB
    uint16_t* wt   = (uint16_t*)d_ws;
    uint16_t* yT   = (uint16_t*)((char*)d_ws + 262144);
    float*    z    = (float*)((char*)d_ws + 262144 + 8388608);
    float*    partb= (float*)((char*)d_ws + 262144 + 8388608 + 16777216);
    int*      degw = (int*)((char*)d_ws + 262144 + 8388608 + 16777216 + 33554432);

    k_transpose_w<<<512, 256, 0, stream>>>(weight, wt);
    k_small_gemm<<<dim3(4, 128), 256, 0, stream>>>(x, wt, bias, yT, z);
    k_big_gemm<<<dim3(256, 2), 512, 0, stream>>>(adj, yT, partb, degw);
    k_reduce<<<4096, 256, 0, stream>>>(partb, degw, z, out);
}